// Round 12
// baseline (226.910 us; speedup 1.0000x reference)
//
#include <hip/hip_runtime.h>
#include <hip/hip_bf16.h>
#include <stdint.h>
#include <stddef.h>

#define NROWS 8192
#define DDIM  512              // floats per input row; ALSO bytes per fp8 row
#define TILE  128
#define BKB   128              // fp8 K-elements (=bytes) per LDS stage
#define NBLK  (NROWS / TILE)   // 64

static_assert(NBLK == 64, "bj extraction assumes 64 col-blocks");

typedef float f32x4 __attribute__((ext_vector_type(4)));
typedef int   i32x4 __attribute__((ext_vector_type(4)));
typedef int   i32x8 __attribute__((ext_vector_type(8)));

// async global->LDS, 16B per lane; LDS dest is wave-uniform base + lane*16
__device__ __forceinline__ void async_copy16(const void* g, void* l) {
    __builtin_amdgcn_global_load_lds(
        (const __attribute__((address_space(1))) uint32_t*)g,
        (__attribute__((address_space(3))) uint32_t*)l,
        16, 0, 0);
}

// -------- prep: zero accumulators + normalize both matrices to fp8 e4m3 --------
// grid = 4096: blocks [0,2048) cxr->cn8, [2048,4096) ehr->en8.
// blocks [0,64) zero rowsum/colsum (64*256 = 16384 = 2N floats); block 0 zeroes out[0].
__global__ __launch_bounds__(256) void prep_kernel(
    const float* __restrict__ CXR, const float* __restrict__ EHR,
    uint32_t* __restrict__ CN8, uint32_t* __restrict__ EN8,
    float* __restrict__ rowsum /* colsum follows contiguously */,
    float* __restrict__ out)
{
    if (blockIdx.x < 64) {
        rowsum[blockIdx.x * 256 + threadIdx.x] = 0.f;
        if (blockIdx.x == 0 && threadIdx.x == 0) out[0] = 0.f;
    }
    const int half = (blockIdx.x >= 2048);
    const float* X = half ? EHR : CXR;
    uint32_t* Y = half ? EN8 : CN8;
    const int row  = (blockIdx.x & 2047) * 4 + (threadIdx.x >> 6);
    const int lane = threadIdx.x & 63;
    const float* xr = X + (size_t)row * DDIM;
    float4 v0 = ((const float4*)xr)[lane];        // elems lane*4   .. +3
    float4 v1 = ((const float4*)xr)[lane + 64];   // elems 256+lane*4 .. +3
    float ss = v0.x*v0.x + v0.y*v0.y + v0.z*v0.z + v0.w*v0.w
             + v1.x*v1.x + v1.y*v1.y + v1.z*v1.z + v1.w*v1.w;
    #pragma unroll
    for (int d = 1; d < 64; d <<= 1) ss += __shfl_xor(ss, d);
    const float sc = 1.0f / fmaxf(sqrtf(ss), 1e-8f);
    uint32_t* yr = Y + (size_t)row * (DDIM / 4);
    int w0 = __builtin_amdgcn_cvt_pk_fp8_f32(v0.x*sc, v0.y*sc, 0, false);
    w0     = __builtin_amdgcn_cvt_pk_fp8_f32(v0.z*sc, v0.w*sc, w0, true);
    int w1 = __builtin_amdgcn_cvt_pk_fp8_f32(v1.x*sc, v1.y*sc, 0, false);
    w1     = __builtin_amdgcn_cvt_pk_fp8_f32(v1.z*sc, v1.w*sc, w1, true);
    yr[lane]      = (uint32_t)w0;   // bytes = elems lane*4..+3 in k order
    yr[lane + 64] = (uint32_t)w1;
}

// -------- fused S = cn·enT GEMM (MX-scaled fp8, 16x16x128, scale=1.0) + exp + reductions ----
// Round-12 (third re-run; rounds 9, 10, 11 were infra acquisition timeouts, no data):
// round-11's double-buffer was a NULL result (131 vs 134 us; MfmaUtil
// 10%, occupancy 10.8% unchanged) -> intra-block ILP is not the missing piece.
// Revised theory: occupancy 10.8% = 1 wave/SIMD = ZERO TLP; every ds_read->MFMA
// latency chain, 4-wave barrier arrival, and epilogue atomic is fully exposed
// (per-block wall ~19.6k cyc vs ~550 cyc of MFMA issue per wave). Round-7's 65us
// baseline worked because ~2.8 blocks/CU hid the same serial structure (m114).
// Fix: __launch_bounds__(256,1) -> (256,2). Unified regs/wave = VGPR 172 + AGPR 64
// = 236 <= 256, so 2 waves/SIMD FITS the current 3-live-tuple structure without
// spilling (round-9's (256,2) spill was the old 5-tuple version). LDS 64 KB ->
// 2 blocks/CU. Spill tripwire: FETCH/WRITE must stay ~18.5/20.5 MB; if WRITE
// balloons, revert to non-scaled 16x16x32 + dbuf (declared fallback).
// MX math unchanged (absmax 0 four clean runs): mfma_scale_f32_16x16x128_f8f6f4,
// scales pinned 0x7F (x1.0), double-buffered LDS, conflict-light swizzled reads.
__global__ __launch_bounds__(256, 2) void gemm_loss_kernel(
    const uint8_t* __restrict__ A,   // cn fp8 [N][512 B]
    const uint8_t* __restrict__ B,   // en fp8 [N][512 B]
    const float* __restrict__ temp_p,
    float* __restrict__ rowsum,
    float* __restrict__ colsum,
    float* __restrict__ diagv)
{
    __shared__ uint8_t As[2][TILE * BKB];   // 2 x 16 KB
    __shared__ uint8_t Bs[2][TILE * BKB];   // 2 x 16 KB

    const int tid  = threadIdx.x;
    const int lane = tid & 63;
    const int wv   = tid >> 6;          // wave 0..3
    const int wi   = (wv >> 1) * 64;    // wave row offset in tile
    const int wj   = (wv & 1) * 64;     // wave col offset in tile
    const int lcol = lane & 15;
    const int q    = lane >> 4;
    const int u0   = q << 1;            // first 16B k-unit this lane feeds to MFMA

    const int bi = blockIdx.x & (NBLK - 1);
    const int bj = blockIdx.x >> 6;
    const int row0 = bi * TILE;
    const int col0 = bj * TILE;

    // staging: wave wv loads rows [wv*32, wv*32+32) of both tiles, 4 chunks of 8 rows
    const int sr = lane >> 3;            // row within 8-row chunk
    const int su = (lane & 7) ^ sr;      // 16B-unit fetched by this lane (swizzle inverse)
    const uint8_t* Ag = A + (size_t)(row0 + wv * 32 + sr) * DDIM + su * 16;
    const uint8_t* Bg = B + (size_t)(col0 + wv * 32 + sr) * DDIM + su * 16;

    f32x4 acc[4][4] = {};
    const int SC1 = 0x7F7F7F7F;          // E8M0 scale 1.0 in every byte

    // issue one stage's 8 async bursts (this wave's 32-row slice of A and B)
    auto stage = [&](int buf, int k0) {
        #pragma unroll
        for (int c = 0; c < 4; ++c) {
            async_copy16(Ag + (size_t)(c * 8) * DDIM + k0, &As[buf][(wv * 32 + c * 8) * BKB]);
            async_copy16(Bg + (size_t)(c * 8) * DDIM + k0, &Bs[buf][(wv * 32 + c * 8) * BKB]);
        }
    };

    stage(0, 0);
    __syncthreads();   // drain stage-0 loads (vmcnt 0) + barrier

    #pragma unroll
    for (int t = 0; t < 4; ++t) {      // t, cur, buf indices all compile-time
        const int cur = t & 1;
        if (t < 3) stage(cur ^ 1, (t + 1) * BKB);   // prefetch next stage, no wait

        #pragma unroll
        for (int nt2 = 0; nt2 < 2; ++nt2) {
            // hold 2 B fragments (16 regs)
            i32x8 bf2[2];
            #pragma unroll
            for (int j = 0; j < 2; ++j) {
                const int r = wj + (nt2 * 2 + j) * 16 + lcol;
                const uint8_t* base = &Bs[cur][r * BKB];
                i32x4 lo = *(const i32x4*)&base[((u0    ) ^ (r & 7)) * 16];
                i32x4 hi = *(const i32x4*)&base[((u0 + 1) ^ (r & 7)) * 16];
                bf2[j] = __builtin_shufflevector(lo, hi, 0, 1, 2, 3, 4, 5, 6, 7);
            }
            // stream A fragments: each built just before its 2 MFMAs, then dead
            #pragma unroll
            for (int mt = 0; mt < 4; ++mt) {
                const int r = wi + mt * 16 + lcol;
                const uint8_t* base = &As[cur][r * BKB];
                i32x4 lo = *(const i32x4*)&base[((u0    ) ^ (r & 7)) * 16];
                i32x4 hi = *(const i32x4*)&base[((u0 + 1) ^ (r & 7)) * 16];
                i32x8 af = __builtin_shufflevector(lo, hi, 0, 1, 2, 3, 4, 5, 6, 7);
                acc[mt][nt2 * 2]     = __builtin_amdgcn_mfma_scale_f32_16x16x128_f8f6f4(
                    af, bf2[0], acc[mt][nt2 * 2],
                    0 /*cbsz: A=fp8 e4m3*/, 0 /*blgp: B=fp8 e4m3*/,
                    0, SC1, 0, SC1);
                acc[mt][nt2 * 2 + 1] = __builtin_amdgcn_mfma_scale_f32_16x16x128_f8f6f4(
                    af, bf2[1], acc[mt][nt2 * 2 + 1],
                    0, 0, 0, SC1, 0, SC1);
            }
        }

        if (t < 3) __syncthreads();   // drains prefetch vmcnt(0) AFTER compute + barrier
    }

    // ---- epilogue: e = exp(s - M) = 2^(c2*acc - c2), M = 1/T (max possible) ----
    const float invT = 1.0f / temp_p[0];
    const float c2   = invT * 1.442695040888963f;   // log2(e)/T

    float rs[4][4];   // per-lane row partials [mt][reg]
    float cs[4];      // per-lane col partials [nt]
    #pragma unroll
    for (int mt = 0; mt < 4; ++mt)
        #pragma unroll
        for (int r = 0; r < 4; ++r) rs[mt][r] = 0.f;
    #pragma unroll
    for (int nt = 0; nt < 4; ++nt) cs[nt] = 0.f;

    #pragma unroll
    for (int mt = 0; mt < 4; ++mt) {
        #pragma unroll
        for (int nt = 0; nt < 4; ++nt) {
            #pragma unroll
            for (int r = 0; r < 4; ++r) {
                // C/D layout: col = lane&15, row = quad*4 + reg  [m89/m91]
                const int gi = row0 + wi + mt * 16 + q * 4 + r;
                const int gj = col0 + wj + nt * 16 + lcol;
                const float a = acc[mt][nt][r];
                float e;
                if (gi == gj) { diagv[gi] = a * invT; e = 0.f; }
                else          { e = __builtin_amdgcn_exp2f(fmaf(a, c2, -c2)); }
                rs[mt][r] += e;
                cs[nt]    += e;
            }
        }
    }

    // row sums: reduce across the 16 columns (lane bits 0..3)
    #pragma unroll
    for (int d = 1; d < 16; d <<= 1)
        #pragma unroll
        for (int mt = 0; mt < 4; ++mt)
            #pragma unroll
            for (int r = 0; r < 4; ++r)
                rs[mt][r] += __shfl_xor(rs[mt][r], d);

    // col sums: reduce across the 4 quads (lane bits 4..5)
    #pragma unroll
    for (int d = 16; d < 64; d <<= 1)
        #pragma unroll
        for (int nt = 0; nt < 4; ++nt)
            cs[nt] += __shfl_xor(cs[nt], d);

    if (lcol == 0) {
        #pragma unroll
        for (int mt = 0; mt < 4; ++mt)
            #pragma unroll
            for (int r = 0; r < 4; ++r)
                atomicAdd(&rowsum[row0 + wi + mt * 16 + q * 4 + r], rs[mt][r]);
    }
    if (q == 0) {
        #pragma unroll
        for (int nt = 0; nt < 4; ++nt)
            atomicAdd(&colsum[col0 + wj + nt * 16 + lcol], cs[nt]);
    }
}

// -------- final scalar: loss = mean_i( 2M + log(rowsum_i) + log(colsum_i) - 2*diag_i ) ----
__global__ __launch_bounds__(256) void finalize_kernel(
    const float* __restrict__ rowsum, const float* __restrict__ colsum,
    const float* __restrict__ diagv,  const float* __restrict__ temp_p,
    float* __restrict__ out)
{
    __shared__ float red[4];
    const float M = 1.0f / temp_p[0];
    const int i = blockIdx.x * 256 + threadIdx.x;
    float s = 2.f * M + logf(rowsum[i]) + logf(colsum[i]) - 2.f * diagv[i];
    #pragma unroll
    for (int d = 1; d < 64; d <<= 1) s += __shfl_xor(s, d);
    if ((threadIdx.x & 63) == 0) red[threadIdx.x >> 6] = s;
    __syncthreads();
    if (threadIdx.x == 0)
        atomicAdd(out, (red[0] + red[1] + red[2] + red[3]) / (float)NROWS);
}

extern "C" void kernel_launch(void* const* d_in, const int* in_sizes, int n_in,
                              void* d_out, int out_size, void* d_ws, size_t ws_size,
                              hipStream_t stream) {
    (void)in_sizes; (void)n_in; (void)out_size; (void)ws_size;
    const float* cxr    = (const float*)d_in[0];
    const float* ehr    = (const float*)d_in[1];
    const float* temp_p = (const float*)d_in[2];
    float* out = (float*)d_out;

    // workspace: rowsum[N] | colsum[N] | diag[N] | cn fp8 [N*512B] | en fp8 (~8.1 MB)
    float* rowsum = (float*)d_ws;
    float* colsum = rowsum + NROWS;
    float* diagv  = colsum + NROWS;
    uint32_t* cn8 = (uint32_t*)(diagv + NROWS);            // 16B-aligned (96 KB offset)
    uint32_t* en8 = cn8 + (size_t)NROWS * (DDIM / 4);
    const uint8_t* cnb = (const uint8_t*)cn8;
    const uint8_t* enb = (const uint8_t*)en8;

    prep_kernel<<<4096, 256, 0, stream>>>(cxr, ehr, cn8, en8, rowsum, out);
    gemm_loss_kernel<<<NBLK * NBLK, 256, 0, stream>>>(cnb, enb, temp_p, rowsum, colsum, diagv);
    finalize_kernel<<<NROWS / 256, 256, 0, stream>>>(rowsum, colsum, diagv, temp_p, out);
}

// Round 14
// 163.899 us; speedup vs baseline: 1.3844x; 1.3844x over previous
//
#include <hip/hip_runtime.h>
#include <hip/hip_bf16.h>
#include <stdint.h>
#include <stddef.h>

#define NROWS 8192
#define DDIM  512              // floats per input row; ALSO bytes per fp8 row
#define TILE  128
#define BKB   128              // fp8 K-elements (=bytes) per LDS stage
#define NBLK  (NROWS / TILE)   // 64

static_assert(NBLK == 64, "bj extraction assumes 64 col-blocks");

typedef float f32x4 __attribute__((ext_vector_type(4)));
typedef long  v2l  __attribute__((ext_vector_type(2)));   // one 16-B LDS read

// async global->LDS, 16B per lane; LDS dest is wave-uniform base + lane*16
__device__ __forceinline__ void async_copy16(const void* g, void* l) {
    __builtin_amdgcn_global_load_lds(
        (const __attribute__((address_space(1))) uint32_t*)g,
        (__attribute__((address_space(3))) uint32_t*)l,
        16, 0, 0);
}

// -------- prep: zero accumulators + normalize both matrices to fp8 e4m3 --------
// grid = 4096: blocks [0,2048) cxr->cn8, [2048,4096) ehr->en8.
// blocks [0,64) zero rowsum/colsum (64*256 = 16384 = 2N floats); block 0 zeroes out[0].
__global__ __launch_bounds__(256) void prep_kernel(
    const float* __restrict__ CXR, const float* __restrict__ EHR,
    uint32_t* __restrict__ CN8, uint32_t* __restrict__ EN8,
    float* __restrict__ rowsum /* colsum follows contiguously */,
    float* __restrict__ out)
{
    if (blockIdx.x < 64) {
        rowsum[blockIdx.x * 256 + threadIdx.x] = 0.f;
        if (blockIdx.x == 0 && threadIdx.x == 0) out[0] = 0.f;
    }
    const int half = (blockIdx.x >= 2048);
    const float* X = half ? EHR : CXR;
    uint32_t* Y = half ? EN8 : CN8;
    const int row  = (blockIdx.x & 2047) * 4 + (threadIdx.x >> 6);
    const int lane = threadIdx.x & 63;
    const float* xr = X + (size_t)row * DDIM;
    float4 v0 = ((const float4*)xr)[lane];        // elems lane*4   .. +3
    float4 v1 = ((const float4*)xr)[lane + 64];   // elems 256+lane*4 .. +3
    float ss = v0.x*v0.x + v0.y*v0.y + v0.z*v0.z + v0.w*v0.w
             + v1.x*v1.x + v1.y*v1.y + v1.z*v1.z + v1.w*v1.w;
    #pragma unroll
    for (int d = 1; d < 64; d <<= 1) ss += __shfl_xor(ss, d);
    const float sc = 1.0f / fmaxf(sqrtf(ss), 1e-8f);
    uint32_t* yr = Y + (size_t)row * (DDIM / 4);
    int w0 = __builtin_amdgcn_cvt_pk_fp8_f32(v0.x*sc, v0.y*sc, 0, false);
    w0     = __builtin_amdgcn_cvt_pk_fp8_f32(v0.z*sc, v0.w*sc, w0, true);
    int w1 = __builtin_amdgcn_cvt_pk_fp8_f32(v1.x*sc, v1.y*sc, 0, false);
    w1     = __builtin_amdgcn_cvt_pk_fp8_f32(v1.z*sc, v1.w*sc, w1, true);
    yr[lane]      = (uint32_t)w0;   // bytes = elems lane*4..+3 in k order
    yr[lane + 64] = (uint32_t)w1;
}

// -------- fused S = cn·enT fp8 GEMM (non-scaled 16x16x32) + exp + reductions --------
// Round-13 (re-run; round-13 bench was an infra acquisition timeout, no data):
// MX-path POST-MORTEM + declared fallback. Two independent runs proved
// the mfma_scale kernel is boxed in: at (256,2) the allocator caps arch VGPR at 128
// (unified-file granule with 64 AGPR) and its ~172-reg need spills (348 MB scratch,
// 155-161 us, rounds 2+12); at (256,1) it fits but runs 1 wave/SIMD with all
// latency exposed (131 us, rounds 4+8, dbuf null). Its 2.27x MFMA-rate advantage
// (~18 us) < its TLP penalty (>=66 us). REVERT to round-0 non-scaled
// mfma_f32_16x16x32_fp8_fp8 (VGPR 64 + AGPR 64 = 128 unified, absmax 0, 65 us gemm
// at ~2.8 blocks/CU, MfmaUtil 42% + VALUBusy 36% = 78% busy), and KEEP the one
// verified win from the arc: the DOUBLE-BUFFERED K-loop (absmax 0, round 8),
// which targets the remaining ~22% barrier-drain: stage t+1 issues into buf^1
// before computing buf, so the vmcnt(0) drain lands after ~2k cyc of ds_read+MFMA.
// LDS 64 KB -> 2 blocks/CU (LDS-bound); __launch_bounds__(256,2): 256-reg budget,
// ~2x what this kernel needs -> no spill risk. Fragment reads: conflict-free b128
// via k-permutation -- lane (m,q) reads 16 B at unit u=kk2*4+q, slot u^(r&7); lo
// 8 B feed MFMA window 2kk2, hi feed 2kk2+1 (same permutation on A and B).
// Tripwires: occupancy ~12% -> LDS/reg accounting wrong; gemm ~= 65 us -> dbuf
// neutral at 2 blocks -> revert to exact round-0, declare near-roofline.
__global__ __launch_bounds__(256, 2) void gemm_loss_kernel(
    const uint8_t* __restrict__ A,   // cn fp8 [N][512 B]
    const uint8_t* __restrict__ B,   // en fp8 [N][512 B]
    const float* __restrict__ temp_p,
    float* __restrict__ rowsum,
    float* __restrict__ colsum,
    float* __restrict__ diagv)
{
    __shared__ uint8_t As[2][TILE * BKB];   // 2 x 16 KB
    __shared__ uint8_t Bs[2][TILE * BKB];   // 2 x 16 KB

    const int tid  = threadIdx.x;
    const int lane = tid & 63;
    const int wv   = tid >> 6;          // wave 0..3
    const int wi   = (wv >> 1) * 64;    // wave row offset in tile
    const int wj   = (wv & 1) * 64;     // wave col offset in tile
    const int lcol = lane & 15;
    const int q    = lane >> 4;

    const int bi = blockIdx.x & (NBLK - 1);
    const int bj = blockIdx.x >> 6;
    const int row0 = bi * TILE;
    const int col0 = bj * TILE;

    // staging: wave wv loads rows [wv*32, wv*32+32) of both tiles, 4 chunks of 8 rows
    const int sr = lane >> 3;            // row within 8-row chunk
    const int su = (lane & 7) ^ sr;      // 16B-unit fetched by this lane (swizzle inverse)
    const uint8_t* Ag = A + (size_t)(row0 + wv * 32 + sr) * DDIM + su * 16;
    const uint8_t* Bg = B + (size_t)(col0 + wv * 32 + sr) * DDIM + su * 16;

    f32x4 acc[4][4] = {};

    // issue one stage's 8 async bursts (this wave's 32-row slice of A and B)
    auto stage = [&](int buf, int k0) {
        #pragma unroll
        for (int c = 0; c < 4; ++c) {
            async_copy16(Ag + (size_t)(c * 8) * DDIM + k0, &As[buf][(wv * 32 + c * 8) * BKB]);
            async_copy16(Bg + (size_t)(c * 8) * DDIM + k0, &Bs[buf][(wv * 32 + c * 8) * BKB]);
        }
    };

    stage(0, 0);
    __syncthreads();   // drain stage-0 loads (vmcnt 0) + barrier

    #pragma unroll
    for (int t = 0; t < 4; ++t) {      // t, cur all compile-time
        const int cur = t & 1;
        if (t < 3) stage(cur ^ 1, (t + 1) * BKB);   // prefetch next stage, no wait

        #pragma unroll
        for (int kk2 = 0; kk2 < 2; ++kk2) {    // each kk2 covers two K=32 windows
            const int u = kk2 * 4 + q;         // this lane's 16B k-unit
            long aflo[4], afhi[4];
            #pragma unroll
            for (int mt = 0; mt < 4; ++mt) {
                const int r = wi + mt * 16 + lcol;
                v2l a16 = *(const v2l*)&As[cur][r * BKB + (u ^ (r & 7)) * 16];
                aflo[mt] = a16.x; afhi[mt] = a16.y;
            }
            // B fragments streamed: one b128 feeds 8 MFMAs (2 windows x 4 m-tiles)
            #pragma unroll
            for (int nt = 0; nt < 4; ++nt) {
                const int r = wj + nt * 16 + lcol;
                v2l b16 = *(const v2l*)&Bs[cur][r * BKB + (u ^ (r & 7)) * 16];
                #pragma unroll
                for (int mt = 0; mt < 4; ++mt)
                    acc[mt][nt] = __builtin_amdgcn_mfma_f32_16x16x32_fp8_fp8(
                        aflo[mt], b16.x, acc[mt][nt], 0, 0, 0);
                #pragma unroll
                for (int mt = 0; mt < 4; ++mt)
                    acc[mt][nt] = __builtin_amdgcn_mfma_f32_16x16x32_fp8_fp8(
                        afhi[mt], b16.y, acc[mt][nt], 0, 0, 0);
            }
        }

        if (t < 3) __syncthreads();   // drains prefetch vmcnt(0) AFTER compute + barrier
    }

    // ---- epilogue: e = exp(s - M) = 2^(c2*acc - c2), M = 1/T (max possible) ----
    const float invT = 1.0f / temp_p[0];
    const float c2   = invT * 1.442695040888963f;   // log2(e)/T

    float rs[4][4];   // per-lane row partials [mt][reg]
    float cs[4];      // per-lane col partials [nt]
    #pragma unroll
    for (int mt = 0; mt < 4; ++mt)
        #pragma unroll
        for (int r = 0; r < 4; ++r) rs[mt][r] = 0.f;
    #pragma unroll
    for (int nt = 0; nt < 4; ++nt) cs[nt] = 0.f;

    #pragma unroll
    for (int mt = 0; mt < 4; ++mt) {
        #pragma unroll
        for (int nt = 0; nt < 4; ++nt) {
            #pragma unroll
            for (int r = 0; r < 4; ++r) {
                // C/D layout: col = lane&15, row = quad*4 + reg  [m89/m91]
                const int gi = row0 + wi + mt * 16 + q * 4 + r;
                const int gj = col0 + wj + nt * 16 + lcol;
                const float a = acc[mt][nt][r];
                float e;
                if (gi == gj) { diagv[gi] = a * invT; e = 0.f; }
                else          { e = __builtin_amdgcn_exp2f(fmaf(a, c2, -c2)); }
                rs[mt][r] += e;
                cs[nt]    += e;
            }
        }
    }

    // row sums: reduce across the 16 columns (lane bits 0..3)
    #pragma unroll
    for (int d = 1; d < 16; d <<= 1)
        #pragma unroll
        for (int mt = 0; mt < 4; ++mt)
            #pragma unroll
            for (int r = 0; r < 4; ++r)
                rs[mt][r] += __shfl_xor(rs[mt][r], d);

    // col sums: reduce across the 4 quads (lane bits 4..5)
    #pragma unroll
    for (int d = 16; d < 64; d <<= 1)
        #pragma unroll
        for (int nt = 0; nt < 4; ++nt)
            cs[nt] += __shfl_xor(cs[nt], d);

    if (lcol == 0) {
        #pragma unroll
        for (int mt = 0; mt < 4; ++mt)
            #pragma unroll
            for (int r = 0; r < 4; ++r)
                atomicAdd(&rowsum[row0 + wi + mt * 16 + q * 4 + r], rs[mt][r]);
    }
    if (q == 0) {
        #pragma unroll
        for (int nt = 0; nt < 4; ++nt)
            atomicAdd(&colsum[col0 + wj + nt * 16 + lcol], cs[nt]);
    }
}

// -------- final scalar: loss = mean_i( 2M + log(rowsum_i) + log(colsum_i) - 2*diag_i ) ----
__global__ __launch_bounds__(256) void finalize_kernel(
    const float* __restrict__ rowsum, const float* __restrict__ colsum,
    const float* __restrict__ diagv,  const float* __restrict__ temp_p,
    float* __restrict__ out)
{
    __shared__ float red[4];
    const float M = 1.0f / temp_p[0];
    const int i = blockIdx.x * 256 + threadIdx.x;
    float s = 2.f * M + logf(rowsum[i]) + logf(colsum[i]) - 2.f * diagv[i];
    #pragma unroll
    for (int d = 1; d < 64; d <<= 1) s += __shfl_xor(s, d);
    if ((threadIdx.x & 63) == 0) red[threadIdx.x >> 6] = s;
    __syncthreads();
    if (threadIdx.x == 0)
        atomicAdd(out, (red[0] + red[1] + red[2] + red[3]) / (float)NROWS);
}

extern "C" void kernel_launch(void* const* d_in, const int* in_sizes, int n_in,
                              void* d_out, int out_size, void* d_ws, size_t ws_size,
                              hipStream_t stream) {
    (void)in_sizes; (void)n_in; (void)out_size; (void)ws_size;
    const float* cxr    = (const float*)d_in[0];
    const float* ehr    = (const float*)d_in[1];
    const float* temp_p = (const float*)d_in[2];
    float* out = (float*)d_out;

    // workspace: rowsum[N] | colsum[N] | diag[N] | cn fp8 [N*512B] | en fp8 (~8.1 MB)
    float* rowsum = (float*)d_ws;
    float* colsum = rowsum + NROWS;
    float* diagv  = colsum + NROWS;
    uint32_t* cn8 = (uint32_t*)(diagv + NROWS);            // 16B-aligned (96 KB offset)
    uint32_t* en8 = cn8 + (size_t)NROWS * (DDIM / 4);
    const uint8_t* cnb = (const uint8_t*)cn8;
    const uint8_t* enb = (const uint8_t*)en8;

    prep_kernel<<<4096, 256, 0, stream>>>(cxr, ehr, cn8, en8, rowsum, out);
    gemm_loss_kernel<<<NBLK * NBLK, 256, 0, stream>>>(cnb, enb, temp_p, rowsum, colsum, diagv);
    finalize_kernel<<<NROWS / 256, 256, 0, stream>>>(rowsum, colsum, diagv, temp_p, out);
}

// Round 15
// 136.295 us; speedup vs baseline: 1.6648x; 1.2025x over previous
//
#include <hip/hip_runtime.h>
#include <hip/hip_bf16.h>
#include <stdint.h>
#include <stddef.h>

#define NROWS 8192
#define DDIM  512              // floats per input row; ALSO bytes per fp8 row
#define TILE  128
#define BKB   128              // fp8 K-elements (=bytes) per LDS stage
#define NBLK  (NROWS / TILE)   // 64

static_assert(NBLK == 64, "bj extraction assumes 64 col-blocks");

typedef float f32x4 __attribute__((ext_vector_type(4)));
typedef long  v2l  __attribute__((ext_vector_type(2)));   // one 16-B LDS read

// async global->LDS, 16B per lane; LDS dest is wave-uniform base + lane*16
__device__ __forceinline__ void async_copy16(const void* g, void* l) {
    __builtin_amdgcn_global_load_lds(
        (const __attribute__((address_space(1))) uint32_t*)g,
        (__attribute__((address_space(3))) uint32_t*)l,
        16, 0, 0);
}

// -------- prep: zero accumulators + normalize both matrices to fp8 e4m3 --------
// grid = 4096: blocks [0,2048) cxr->cn8, [2048,4096) ehr->en8.
// blocks [0,64) zero rowsum/colsum (64*256 = 16384 = 2N floats); block 0 zeroes out[0].
__global__ __launch_bounds__(256) void prep_kernel(
    const float* __restrict__ CXR, const float* __restrict__ EHR,
    uint32_t* __restrict__ CN8, uint32_t* __restrict__ EN8,
    float* __restrict__ rowsum /* colsum follows contiguously */,
    float* __restrict__ out)
{
    if (blockIdx.x < 64) {
        rowsum[blockIdx.x * 256 + threadIdx.x] = 0.f;
        if (blockIdx.x == 0 && threadIdx.x == 0) out[0] = 0.f;
    }
    const int half = (blockIdx.x >= 2048);
    const float* X = half ? EHR : CXR;
    uint32_t* Y = half ? EN8 : CN8;
    const int row  = (blockIdx.x & 2047) * 4 + (threadIdx.x >> 6);
    const int lane = threadIdx.x & 63;
    const float* xr = X + (size_t)row * DDIM;
    float4 v0 = ((const float4*)xr)[lane];        // elems lane*4   .. +3
    float4 v1 = ((const float4*)xr)[lane + 64];   // elems 256+lane*4 .. +3
    float ss = v0.x*v0.x + v0.y*v0.y + v0.z*v0.z + v0.w*v0.w
             + v1.x*v1.x + v1.y*v1.y + v1.z*v1.z + v1.w*v1.w;
    #pragma unroll
    for (int d = 1; d < 64; d <<= 1) ss += __shfl_xor(ss, d);
    const float sc = 1.0f / fmaxf(sqrtf(ss), 1e-8f);
    uint32_t* yr = Y + (size_t)row * (DDIM / 4);
    int w0 = __builtin_amdgcn_cvt_pk_fp8_f32(v0.x*sc, v0.y*sc, 0, false);
    w0     = __builtin_amdgcn_cvt_pk_fp8_f32(v0.z*sc, v0.w*sc, w0, true);
    int w1 = __builtin_amdgcn_cvt_pk_fp8_f32(v1.x*sc, v1.y*sc, 0, false);
    w1     = __builtin_amdgcn_cvt_pk_fp8_f32(v1.z*sc, v1.w*sc, w1, true);
    yr[lane]      = (uint32_t)w0;   // bytes = elems lane*4..+3 in k order
    yr[lane + 64] = (uint32_t)w1;
}

// -------- fused S = cn·enT fp8 GEMM (non-scaled 16x16x32) + exp + reductions --------
// Round-15: REVERT to the measured-best round-0 configuration. Season evidence:
//   single-buffer 32KB (256,4) @2.8 blk/CU -> gemm 65 us  (round 0, BEST)
//   MX 16x16x128 @(256,1..3)               -> 131-324 us  (spill or zero-TLP box)
//   dbuf 64KB (256,2) @1.7 blk/CU          -> 99 us       (round 14: -1.1 blk
//                                             co-residency cost > prefetch gain;
//                                             MFMA busy identical ~27 us both ways)
// Conclusion (3x measured): cross-block TLP at 2.8 blocks/CU is the best latency
// hider available to this structure; every LDS/register change that lowered
// co-residency lost more than its pipelining gained. Single carried-over delta vs
// round 0: the exp2(fma) epilogue (verified absmax 0 in rounds 12/14, same C/D
// indexing) -- e = exp(s-M) = 2^(c2*acc - c2), c2 = log2(e)/T, saves 2 VALU
// ops/elem. 256 thr / 4 waves, wave tile 64x64, acc 4x4 f32x4 (AGPRs), VGPR 64 +
// AGPR 64 = 128 unified -> (256,4) cap fits exactly. Fragment reads: conflict-free
// b128 via k-permutation -- lane (m,q) reads 16 B at unit u=kk2*4+q, slot u^(r&7);
// lo 8 B feed MFMA window 2kk2, hi feed 2kk2+1 (same permutation on A and B =>
// dot products unchanged).
__global__ __launch_bounds__(256, 4) void gemm_loss_kernel(
    const uint8_t* __restrict__ A,   // cn fp8 [N][512 B]
    const uint8_t* __restrict__ B,   // en fp8 [N][512 B]
    const float* __restrict__ temp_p,
    float* __restrict__ rowsum,
    float* __restrict__ colsum,
    float* __restrict__ diagv)
{
    __shared__ uint8_t As[TILE * BKB];   // 16 KB
    __shared__ uint8_t Bs[TILE * BKB];   // 16 KB

    const int tid  = threadIdx.x;
    const int lane = tid & 63;
    const int wv   = tid >> 6;          // wave 0..3
    const int wi   = (wv >> 1) * 64;    // wave row offset in tile
    const int wj   = (wv & 1) * 64;     // wave col offset in tile
    const int lcol = lane & 15;
    const int q    = lane >> 4;

    const int bi = blockIdx.x & (NBLK - 1);
    const int bj = blockIdx.x >> 6;
    const int row0 = bi * TILE;
    const int col0 = bj * TILE;

    // staging: wave wv loads rows [wv*32, wv*32+32) of both tiles, 4 chunks of 8 rows
    const int sr = lane >> 3;            // row within 8-row chunk
    const int su = (lane & 7) ^ sr;      // 16B-unit fetched by this lane (swizzle inverse)
    const uint8_t* Ag = A + (size_t)(row0 + wv * 32 + sr) * DDIM + su * 16;
    const uint8_t* Bg = B + (size_t)(col0 + wv * 32 + sr) * DDIM + su * 16;

    f32x4 acc[4][4] = {};

    for (int k0 = 0; k0 < DDIM; k0 += BKB) {   // 4 stages
        __syncthreads();   // previous stage's LDS reads done before overwrite
        #pragma unroll
        for (int c = 0; c < 4; ++c) {
            async_copy16(Ag + (size_t)(c * 8) * DDIM + k0, &As[(wv * 32 + c * 8) * BKB]);
            async_copy16(Bg + (size_t)(c * 8) * DDIM + k0, &Bs[(wv * 32 + c * 8) * BKB]);
        }
        __syncthreads();   // drains vmcnt before s_barrier

        #pragma unroll
        for (int kk2 = 0; kk2 < 2; ++kk2) {    // each kk2 covers two K=32 windows
            const int u = kk2 * 4 + q;         // this lane's 16B k-unit
            long aflo[4], afhi[4];
            #pragma unroll
            for (int mt = 0; mt < 4; ++mt) {
                const int r = wi + mt * 16 + lcol;
                v2l a16 = *(const v2l*)&As[r * BKB + (u ^ (r & 7)) * 16];
                aflo[mt] = a16.x; afhi[mt] = a16.y;
            }
            // B fragments streamed: one b128 feeds 8 MFMAs (2 windows x 4 m-tiles)
            #pragma unroll
            for (int nt = 0; nt < 4; ++nt) {
                const int r = wj + nt * 16 + lcol;
                v2l b16 = *(const v2l*)&Bs[r * BKB + (u ^ (r & 7)) * 16];
                #pragma unroll
                for (int mt = 0; mt < 4; ++mt)
                    acc[mt][nt] = __builtin_amdgcn_mfma_f32_16x16x32_fp8_fp8(
                        aflo[mt], b16.x, acc[mt][nt], 0, 0, 0);
                #pragma unroll
                for (int mt = 0; mt < 4; ++mt)
                    acc[mt][nt] = __builtin_amdgcn_mfma_f32_16x16x32_fp8_fp8(
                        afhi[mt], b16.y, acc[mt][nt], 0, 0, 0);
            }
        }
    }

    // ---- epilogue: e = exp(s - M) = 2^(c2*acc - c2), M = 1/T (max possible) ----
    const float invT = 1.0f / temp_p[0];
    const float c2   = invT * 1.442695040888963f;   // log2(e)/T

    float rs[4][4];   // per-lane row partials [mt][reg]
    float cs[4];      // per-lane col partials [nt]
    #pragma unroll
    for (int mt = 0; mt < 4; ++mt)
        #pragma unroll
        for (int r = 0; r < 4; ++r) rs[mt][r] = 0.f;
    #pragma unroll
    for (int nt = 0; nt < 4; ++nt) cs[nt] = 0.f;

    #pragma unroll
    for (int mt = 0; mt < 4; ++mt) {
        #pragma unroll
        for (int nt = 0; nt < 4; ++nt) {
            #pragma unroll
            for (int r = 0; r < 4; ++r) {
                // C/D layout: col = lane&15, row = quad*4 + reg  [m89/m91]
                const int gi = row0 + wi + mt * 16 + q * 4 + r;
                const int gj = col0 + wj + nt * 16 + lcol;
                const float a = acc[mt][nt][r];
                float e;
                if (gi == gj) { diagv[gi] = a * invT; e = 0.f; }
                else          { e = __builtin_amdgcn_exp2f(fmaf(a, c2, -c2)); }
                rs[mt][r] += e;
                cs[nt]    += e;
            }
        }
    }

    // row sums: reduce across the 16 columns (lane bits 0..3)
    #pragma unroll
    for (int d = 1; d < 16; d <<= 1)
        #pragma unroll
        for (int mt = 0; mt < 4; ++mt)
            #pragma unroll
            for (int r = 0; r < 4; ++r)
                rs[mt][r] += __shfl_xor(rs[mt][r], d);

    // col sums: reduce across the 4 quads (lane bits 4..5)
    #pragma unroll
    for (int d = 16; d < 64; d <<= 1)
        #pragma unroll
        for (int nt = 0; nt < 4; ++nt)
            cs[nt] += __shfl_xor(cs[nt], d);

    if (lcol == 0) {
        #pragma unroll
        for (int mt = 0; mt < 4; ++mt)
            #pragma unroll
            for (int r = 0; r < 4; ++r)
                atomicAdd(&rowsum[row0 + wi + mt * 16 + q * 4 + r], rs[mt][r]);
    }
    if (q == 0) {
        #pragma unroll
        for (int nt = 0; nt < 4; ++nt)
            atomicAdd(&colsum[col0 + wj + nt * 16 + lcol], cs[nt]);
    }
}

// -------- final scalar: loss = mean_i( 2M + log(rowsum_i) + log(colsum_i) - 2*diag_i ) ----
__global__ __launch_bounds__(256) void finalize_kernel(
    const float* __restrict__ rowsum, const float* __restrict__ colsum,
    const float* __restrict__ diagv,  const float* __restrict__ temp_p,
    float* __restrict__ out)
{
    __shared__ float red[4];
    const float M = 1.0f / temp_p[0];
    const int i = blockIdx.x * 256 + threadIdx.x;
    float s = 2.f * M + logf(rowsum[i]) + logf(colsum[i]) - 2.f * diagv[i];
    #pragma unroll
    for (int d = 1; d < 64; d <<= 1) s += __shfl_xor(s, d);
    if ((threadIdx.x & 63) == 0) red[threadIdx.x >> 6] = s;
    __syncthreads();
    if (threadIdx.x == 0)
        atomicAdd(out, (red[0] + red[1] + red[2] + red[3]) / (float)NROWS);
}

extern "C" void kernel_launch(void* const* d_in, const int* in_sizes, int n_in,
                              void* d_out, int out_size, void* d_ws, size_t ws_size,
                              hipStream_t stream) {
    (void)in_sizes; (void)n_in; (void)out_size; (void)ws_size;
    const float* cxr    = (const float*)d_in[0];
    const float* ehr    = (const float*)d_in[1];
    const float* temp_p = (const float*)d_in[2];
    float* out = (float*)d_out;

    // workspace: rowsum[N] | colsum[N] | diag[N] | cn fp8 [N*512B] | en fp8 (~8.1 MB)
    float* rowsum = (float*)d_ws;
    float* colsum = rowsum + NROWS;
    float* diagv  = colsum + NROWS;
    uint32_t* cn8 = (uint32_t*)(diagv + NROWS);            // 16B-aligned (96 KB offset)
    uint32_t* en8 = cn8 + (size_t)NROWS * (DDIM / 4);
    const uint8_t* cnb = (const uint8_t*)cn8;
    const uint8_t* enb = (const uint8_t*)en8;

    prep_kernel<<<4096, 256, 0, stream>>>(cxr, ehr, cn8, en8, rowsum, out);
    gemm_loss_kernel<<<NBLK * NBLK, 256, 0, stream>>>(cnb, enb, temp_p, rowsum, colsum, diagv);
    finalize_kernel<<<NROWS / 256, 256, 0, stream>>>(rowsum, colsum, diagv, temp_p, out);
}